// Round 13
// baseline (163.600 us; speedup 1.0000x reference)
//
#include <hip/hip_runtime.h>

#define T_TOK 32768   // B*S
#define NQ    8
#define FFN   2048
#define EMB   512
#define BM    256     // tokens per block (4 waves x 64 tok)
#define BN    128     // cols per block
#define BK    32
#define NCHUNK (FFN / BK)   // 64

typedef __attribute__((ext_vector_type(8)))  short short8;
typedef __attribute__((ext_vector_type(16))) float f32x16;
typedef __attribute__((ext_vector_type(2)))  unsigned int u32x2;

__device__ __forceinline__ unsigned short f2bf(float f) {
  unsigned int u = __float_as_uint(f);
  u += 0x7fffu + ((u >> 16) & 1u);
  return (unsigned short)(u >> 16);
}

__device__ __forceinline__ unsigned pk2bf(float lo, float hi) {
#if __has_builtin(__builtin_amdgcn_cvt_pk_bf16_f32)
  typedef __attribute__((ext_vector_type(2))) __bf16 bf2;
  bf2 p = __builtin_amdgcn_cvt_pk_bf16_f32(lo, hi);
  return *(unsigned*)&p;
#else
  return (unsigned)f2bf(lo) | ((unsigned)f2bf(hi) << 16);
#endif
}

// ---------------------------------------------------------------------------
// prep_all: W2[FFN][EMB] fp32 -> w2t[EMB][FFN] bf16 (tiled transpose), plus
//   w1t16[f][16]: k<8 = W1[k][f], k==8 = b1[f] (bias folded as extra input
//   row; main kernel's bq supplies 1.0 there), k>8 = 0.   (R10/R11-verified)
// ---------------------------------------------------------------------------
__global__ void prep_all(const float* __restrict__ W1,
                         const float* __restrict__ b1,
                         const float* __restrict__ W2,
                         unsigned short* __restrict__ w1t,
                         unsigned short* __restrict__ w2t) {
  __shared__ float t[32][33];
  const int kb = blockIdx.x * 32;   // FFN tile
  const int nb = blockIdx.y * 32;   // EMB tile
  const int tid = threadIdx.x;
  const int c = tid & 31, r0 = tid >> 5;
#pragma unroll
  for (int p = 0; p < 4; ++p) {
    int r = r0 + p * 8;
    t[r][c] = W2[(size_t)(kb + r) * EMB + nb + c];
  }
  __syncthreads();
#pragma unroll
  for (int p = 0; p < 4; ++p) {
    int r = r0 + p * 8;
    w2t[(size_t)(nb + r) * FFN + kb + c] = f2bf(t[c][r]);
  }
  if (blockIdx.x == 0) {
    const int f     = blockIdx.y * 128 + (tid >> 1);
    const int khalf = tid & 1;
    unsigned short v8[8];
#pragma unroll
    for (int j = 0; j < 8; ++j) {
      const int k = khalf * 8 + j;
      float val = (k < 8) ? W1[(size_t)k * FFN + f]
                          : (k == 8 ? b1[f] : 0.f);
      v8[j] = f2bf(val);
    }
    *(uint4*)(w1t + (size_t)f * 16 + khalf * 8) = *(uint4*)v8;
  }
}

// ---------------------------------------------------------------------------
// Fused main, R15: A-SIDE REUSE — 64-token waves, each B-frag feeds 2 MFMAs.
//   R11 accounting: LDS pipe was the busiest resource (160 KB/period/CU ~=
//   1250cy, 40% > MFMA 35%) at a 1:1 ds_read:MFMA ratio. This round: wave =
//   64 tok x 128 col -> per period 8 ds_reads feed 16 GEMM2-MFMAs (2:1),
//   LDS traffic halves to 80 KB/period/CU (~625cy), below the MFMA term.
//   - Block = 256 tok x 128 col (4 waves); grid (128,4)=512 blocks = 2/CU.
//   - aw loaded once, used by both token-groups' gemm1 (2 MFMA/period).
//   - acc = 8 x f32x16 = 128 AGPR (same envelope as R11: arch ~110).
//   - Staging/swizzle formulas identical to R11 (2 issues instead of 4);
//     read de-swizzle unchanged (nt-independent).
//   - No setprio, no manual rotation (R14: both negative); compiler
//     schedules the read/MFMA stream.
//   Spill tripwires: VGPR <= 128, WRITE_SIZE exactly 65536 KB.
// ---------------------------------------------------------------------------
__global__ __launch_bounds__(256, 2) void ffq_main(
    const float* __restrict__ x,
    const float* __restrict__ theta,
    const unsigned short* __restrict__ w1t,
    const unsigned short* __restrict__ w2t,
    const float* __restrict__ b2,
    float* __restrict__ out) {

  __shared__ __align__(16) unsigned short w2_lds[2][BN * BK];   // 16384 B

  const int tid  = threadIdx.x;
  const int wave = tid >> 6;
  const int lane = tid & 63;
  const int nl   = lane & 31;
  const int hi   = lane >> 5;
  const int tok0 = blockIdx.x * BM;
  const int n0   = blockIdx.y * BN;

  // ---- bq0/bq1: B[k=q][tok] for the wave's two 32-token groups ----
  float cth[8];
  {
    const float4* tp = (const float4*)theta;
    float4 t0 = tp[0], t1 = tp[1];
    cth[0] = __cosf(t0.x); cth[1] = __cosf(t0.y);
    cth[2] = __cosf(t0.z); cth[3] = __cosf(t0.w);
    cth[4] = __cosf(t1.x); cth[5] = __cosf(t1.y);
    cth[6] = __cosf(t1.z); cth[7] = __cosf(t1.w);
  }
  short8 bq0, bq1;
#pragma unroll
  for (int g = 0; g < 2; ++g) {
    const float4* xp = (const float4*)(
        x + (size_t)(tok0 + wave * 64 + g * 32 + nl) * NQ);
    float4 x0 = xp[0], x1 = xp[1];
    float q0 = __cosf(x0.x) * cth[0], q1 = __cosf(x0.y) * cth[1];
    float q2 = __cosf(x0.z) * cth[2], q3 = __cosf(x0.w) * cth[3];
    float q4 = __cosf(x1.x) * cth[4], q5 = __cosf(x1.y) * cth[5];
    float q6 = __cosf(x1.z) * cth[6], q7 = __cosf(x1.w) * cth[7];
    uint4 uu;
    uu.x = pk2bf(q0, q1); uu.y = pk2bf(q2, q3);
    uu.z = pk2bf(q4, q5); uu.w = pk2bf(q6, q7);
    if (hi) { uu.x = 0x00003f80u; uu.y = 0; uu.z = 0; uu.w = 0; }  // k=8: 1.0
    if (g == 0) bq0 = *(short8*)&uu; else bq1 = *(short8*)&uu;
  }

  // ---- w2 staging: linear LDS dest, pre-swizzled global source ----
  // stored 16B-chunk c of row r holds global chunk c ^ ((r>>1)&3);
  // r = issue*64 + (tid>>2), c = tid&3  ->  gc = (tid&3) ^ ((tid>>3)&3).
  const int st_gc = (tid & 3) ^ ((tid >> 3) & 3);
  auto stage_w2 = [&](int kc_, int b_) {
    const int k0_ = kc_ * BK;
#pragma unroll
    for (int issue = 0; issue < 2; ++issue) {
      const int r = issue * 64 + (tid >> 2);
      __builtin_amdgcn_global_load_lds(
          (const __attribute__((address_space(1))) void*)(
              w2t + (size_t)(n0 + r) * FFN + k0_ + st_gc * 8),
          (__attribute__((address_space(3))) void*)(
              &w2_lds[b_][issue * 2048 + tid * 8]),
          16, 0, 0);
    }
  };

  // ---- GEMM2 B-frag read offsets (de-swizzle; col-tile-independent) ----
  const int swz  = (nl >> 1) & 3;
  const int off0 = nl * 32 + ((0 + hi) ^ swz) * 8;   // ks=0
  const int off1 = nl * 32 + ((2 + hi) ^ swz) * 8;   // ks=1

  // acc[g*4+nt]: token-group g (0/1), col-tile nt (0..3)
  f32x16 acc[8];
#pragma unroll
  for (int i = 0; i < 8; ++i)
#pragma unroll
    for (int r = 0; r < 16; ++r) acc[i][r] = 0.f;

  // ---- GEMM1 -> A-frags (R7/R10/R11-verified permlane routing) ----
  auto gemm1 = [&](short8 aw, short8 bq, short8& oA, short8& oB) {
    f32x16 c1;
#pragma unroll
    for (int r = 0; r < 16; ++r) c1[r] = 0.f;
    c1 = __builtin_amdgcn_mfma_f32_32x32x16_bf16(aw, bq, c1, 0, 0, 0);
    unsigned Q[8];
#pragma unroll
    for (int p = 0; p < 8; ++p) {
      float lo = c1[2 * p]     > 0.f ? c1[2 * p]     : 0.f;
      float hl = c1[2 * p + 1] > 0.f ? c1[2 * p + 1] : 0.f;
      Q[p] = pk2bf(lo, hl);
    }
    u32x2 s0 = __builtin_amdgcn_permlane32_swap(Q[0], Q[2], false, false);
    u32x2 s1 = __builtin_amdgcn_permlane32_swap(Q[1], Q[3], false, false);
    u32x2 s2 = __builtin_amdgcn_permlane32_swap(Q[4], Q[6], false, false);
    u32x2 s3 = __builtin_amdgcn_permlane32_swap(Q[5], Q[7], false, false);
    uint4 uA; uA.x = s0[0]; uA.y = s1[0]; uA.z = s0[1]; uA.w = s1[1];
    uint4 uB; uB.x = s2[0]; uB.y = s3[0]; uB.z = s2[1]; uB.w = s3[1];
    oA = *(short8*)&uA;
    oB = *(short8*)&uB;
  };

  // ---- prologue: stage chunk 0; GEMM1(0) for both token groups ----
  short8 afA0_c, afB0_c, afA1_c, afB1_c;
  short8 afA0_n, afB0_n, afA1_n, afB1_n;
  {
    stage_w2(0, 0);
    short8 aw0 = *(const short8*)(w1t + (size_t)nl * 16 + hi * 8);
    gemm1(aw0, bq0, afA0_c, afB0_c);
    gemm1(aw0, bq1, afA1_c, afB1_c);
  }

#define MF(a, b, c) __builtin_amdgcn_mfma_f32_32x32x16_bf16((a), (b), (c), 0, 0, 0)

#pragma unroll 2
  for (int kc = 0; kc < NCHUNK; ++kc) {
    const int b  = kc & 1;
    const int nc = (kc + 1 < NCHUNK) ? kc + 1 : NCHUNK - 1;  // clamp: uniform

    // stage(kc) had a full chunk of compute to land -> near-free drain
    asm volatile("s_waitcnt vmcnt(0)" ::: "memory");
    __builtin_amdgcn_s_barrier();   // w2[b] ready; readers of w2[b^1] done
    __builtin_amdgcn_sched_barrier(0);

    // aw for GEMM1(nc) — one load, used by both token groups
    short8 aw = *(const short8*)(w1t + (size_t)(nc * BK + nl) * 16 + hi * 8);

    stage_w2(nc, b ^ 1);            // prefetch next chunk (stays in flight)

    const unsigned short* sb = &w2_lds[b][0];

    // ---- GEMM2(kc): 8 B-frag reads, each feeding 2 MFMAs (A-reuse) ----
#pragma unroll
    for (int nt = 0; nt < 4; ++nt) {
      short8 bf = *(const short8*)(sb + off0 + nt * 1024);   // ks=0
      acc[nt]     = MF(afA0_c, bf, acc[nt]);
      acc[4 + nt] = MF(afA1_c, bf, acc[4 + nt]);
    }
#pragma unroll
    for (int nt = 0; nt < 4; ++nt) {
      short8 bf = *(const short8*)(sb + off1 + nt * 1024);   // ks=1
      acc[nt]     = MF(afB0_c, bf, acc[nt]);
      acc[4 + nt] = MF(afB1_c, bf, acc[4 + nt]);
    }

    // ---- GEMM1(nc) x2: VALU chains hide under the MFMA cluster above ----
    gemm1(aw, bq0, afA0_n, afB0_n);
    gemm1(aw, bq1, afA1_n, afB1_n);
    afA0_c = afA0_n; afB0_c = afB0_n;
    afA1_c = afA1_n; afB1_c = afB1_n;
  }
#undef MF

  // drain the clamped last prefetch before LDS goes away
  asm volatile("s_waitcnt vmcnt(0)" ::: "memory");

  // ---- epilogue: + b2, fp32 store ----
#pragma unroll
  for (int g = 0; g < 2; ++g) {
#pragma unroll
    for (int nt = 0; nt < 4; ++nt) {
      const int col = n0 + nt * 32 + nl;
      const float bv = b2[col];
      const int rbase = tok0 + wave * 64 + g * 32 + 4 * hi;
#pragma unroll
      for (int g2 = 0; g2 < 4; ++g2)
#pragma unroll
        for (int rr = 0; rr < 4; ++rr)
          out[(size_t)(rbase + 8 * g2 + rr) * EMB + col] =
              acc[g * 4 + nt][4 * g2 + rr] + bv;
    }
  }
}

extern "C" void kernel_launch(void* const* d_in, const int* in_sizes, int n_in,
                              void* d_out, int out_size, void* d_ws, size_t ws_size,
                              hipStream_t stream) {
  const float* x     = (const float*)d_in[0];
  const float* theta = (const float*)d_in[1];
  const float* W1    = (const float*)d_in[2];
  const float* b1    = (const float*)d_in[3];
  const float* W2    = (const float*)d_in[4];
  const float* b2    = (const float*)d_in[5];
  float* out = (float*)d_out;

  unsigned short* w1t = (unsigned short*)d_ws;       // FFN*16 = 32768 bf16
  unsigned short* w2t = w1t + FFN * 16;              // 1048576 bf16 [EMB][FFN]

  prep_all<<<dim3(FFN / 32, EMB / 32), 256, 0, stream>>>(W1, b1, W2, w1t, w2t);

  dim3 grid(T_TOK / BM, EMB / BN);  // (128, 4) = 512 blocks = 2/CU
  ffq_main<<<grid, 256, 0, stream>>>(x, theta, w1t, w2t, b2, out);
}